// Round 6
// baseline (183.635 us; speedup 1.0000x reference)
//
#include <hip/hip_runtime.h>

// TokenSelector: out[b,h,q,s,:] = kv[b,h,indices[b,h,q,s],:]
// kv (2,16,4096,128) f32, indices (2,16,512,64) int32, out (2,16,512,64,128) f32.
// R5: exact R3 structure (XCD-aware bh partitioning, 4-way MLP unroll) with ONE
// variable flipped: regular stores instead of nontemporal. Isolates the nt-store
// contribution to R3's 119.4 us. (R4's prefetch + nt-idx both reverted: the
// prefetch sink serialized phase starts, nt idx loads broke 8-wave line reuse.)

namespace {
typedef float f32x4 __attribute__((ext_vector_type(4)));

constexpr int NXCD = 8;
constexpr int BH = 32;                      // B*H
constexpr int BH_PER_XCD = BH / NXCD;       // 4
constexpr long long W_BH = 32768LL * 32;    // f32x4 per bh output slice = 1,048,576

__global__ void token_selector_gather(const f32x4* __restrict__ kv,
                                      const int* __restrict__ idx,
                                      f32x4* __restrict__ out) {
    const int xcd = blockIdx.x & (NXCD - 1);          // physical XCD (round-robin)
    const int xblk = blockIdx.x / NXCD;               // block index within XCD
    const long long tix = (long long)xblk * blockDim.x + threadIdx.x;
    const long long xthreads = (long long)(gridDim.x / NXCD) * blockDim.x; // 65536

    for (int pb = 0; pb < BH_PER_XCD; ++pb) {
        const long long bh = (long long)xcd * BH_PER_XCD + pb;
        const long long out_base = bh * W_BH;
        const long long row_base = bh << 15;          // 32768 gather rows per bh
        const long long kv_base = bh << 17;           // bh * 131072 (f32x4)

        long long i = tix;
        // W_BH / xthreads = 16 iterations -> 4 macro-iters of unroll-4, no tail.
        for (; i + 3 * xthreads < W_BH; i += 4 * xthreads) {
            const long long ia = i;
            const long long ib = i + xthreads;
            const long long ic = i + 2 * xthreads;
            const long long id = i + 3 * xthreads;
            const int ra = idx[row_base + (ia >> 5)];
            const int rb = idx[row_base + (ib >> 5)];
            const int rc = idx[row_base + (ic >> 5)];
            const int rd = idx[row_base + (id >> 5)];
            const f32x4 va = kv[kv_base + ((long long)ra << 5) + (ia & 31)];
            const f32x4 vb = kv[kv_base + ((long long)rb << 5) + (ib & 31)];
            const f32x4 vc = kv[kv_base + ((long long)rc << 5) + (ic & 31)];
            const f32x4 vd = kv[kv_base + ((long long)rd << 5) + (id & 31)];
            out[out_base + ia] = va;
            out[out_base + ib] = vb;
            out[out_base + ic] = vc;
            out[out_base + id] = vd;
        }
        for (; i < W_BH; i += xthreads) {
            const int r = idx[row_base + (i >> 5)];
            out[out_base + i] = kv[kv_base + ((long long)r << 5) + (i & 31)];
        }
    }
}
} // namespace

extern "C" void kernel_launch(void* const* d_in, const int* in_sizes, int n_in,
                              void* d_out, int out_size, void* d_ws, size_t ws_size,
                              hipStream_t stream) {
    const f32x4* kv = (const f32x4*)d_in[0];
    const int* idx = (const int*)d_in[1];
    f32x4* out = (f32x4*)d_out;

    const int block = 256;
    const int grid = 2048;  // 256 blocks per XCD; fully resident (8 blk/CU)
    token_selector_gather<<<grid, block, 0, stream>>>(kv, idx, out);
}

// Round 8
// 103.603 us; speedup vs baseline: 1.7725x; 1.7725x over previous
//
#include <hip/hip_runtime.h>

// TokenSelector: out[b,h,q,s,:] = kv[b,h,indices[b,h,q,s],:]
// kv (2,16,4096,128) f32, indices (2,16,512,64) int32, out (2,16,512,64,128) f32.
// R7: R3 structure (XCD-aware bh partitioning, 4-way MLP unroll, nt stores)
// with phase synchronization via 4 SEQUENTIAL KERNEL LAUNCHES (stream order =
// global barrier) instead of R6's cooperative grid.sync (which failed launch).
// Each launch: every XCD gathers from exactly ONE 2 MiB kv slice -> L2 working
// set = 1 slice + 128 KiB idx, no drift thrash.

namespace {
typedef float f32x4 __attribute__((ext_vector_type(4)));

constexpr int NXCD = 8;
constexpr int BH_PER_XCD = 4;               // 32 bh slices / 8 XCDs
constexpr long long W_BH = 32768LL * 32;    // f32x4 per bh output slice = 1,048,576

__global__ void token_selector_phase(const f32x4* __restrict__ kv,
                                     const int* __restrict__ idx,
                                     f32x4* __restrict__ out,
                                     int pb) {
    const int xcd = blockIdx.x & (NXCD - 1);          // physical XCD (round-robin)
    const int xblk = blockIdx.x / NXCD;               // block index within XCD
    const long long tix = (long long)xblk * blockDim.x + threadIdx.x;
    const long long xthreads = (long long)(gridDim.x / NXCD) * blockDim.x; // 65536

    const long long bh = (long long)xcd * BH_PER_XCD + pb;
    const long long out_base = bh * W_BH;
    const long long row_base = bh << 15;              // 32768 gather rows per bh
    const long long kv_base = bh << 17;               // bh * 131072 (f32x4)

    long long i = tix;
    // W_BH / xthreads = 16 iterations -> 4 macro-iters of unroll-4, no tail.
    for (; i + 3 * xthreads < W_BH; i += 4 * xthreads) {
        const long long ia = i;
        const long long ib = i + xthreads;
        const long long ic = i + 2 * xthreads;
        const long long id = i + 3 * xthreads;
        const int ra = idx[row_base + (ia >> 5)];
        const int rb = idx[row_base + (ib >> 5)];
        const int rc = idx[row_base + (ic >> 5)];
        const int rd = idx[row_base + (id >> 5)];
        const f32x4 va = kv[kv_base + ((long long)ra << 5) + (ia & 31)];
        const f32x4 vb = kv[kv_base + ((long long)rb << 5) + (ib & 31)];
        const f32x4 vc = kv[kv_base + ((long long)rc << 5) + (ic & 31)];
        const f32x4 vd = kv[kv_base + ((long long)rd << 5) + (id & 31)];
        __builtin_nontemporal_store(va, &out[out_base + ia]);
        __builtin_nontemporal_store(vb, &out[out_base + ib]);
        __builtin_nontemporal_store(vc, &out[out_base + ic]);
        __builtin_nontemporal_store(vd, &out[out_base + id]);
    }
    for (; i < W_BH; i += xthreads) {
        const int r = idx[row_base + (i >> 5)];
        const f32x4 v = kv[kv_base + ((long long)r << 5) + (i & 31)];
        __builtin_nontemporal_store(v, &out[out_base + i]);
    }
}
} // namespace

extern "C" void kernel_launch(void* const* d_in, const int* in_sizes, int n_in,
                              void* d_out, int out_size, void* d_ws, size_t ws_size,
                              hipStream_t stream) {
    const f32x4* kv = (const f32x4*)d_in[0];
    const int* idx = (const int*)d_in[1];
    f32x4* out = (f32x4*)d_out;

    const int block = 256;
    const int grid = 2048;  // 256 blocks per XCD; fully resident (8 blk/CU)
    for (int pb = 0; pb < BH_PER_XCD; ++pb) {
        token_selector_phase<<<grid, block, 0, stream>>>(kv, idx, out, pb);
    }
}